// Round 4
// baseline (202.499 us; speedup 1.0000x reference)
//
#include <hip/hip_runtime.h>

// DistMult decoder, R3: dimension-phased gather to fit the per-XCD L2.
//
// R2 post-mortem: x_f16 (6.4 MB) on a 4 MiB per-XCD L2 gives the statistical
// ~62% hit rate for random gathers; we measured exactly that. Fix: split x
// into x_lo (dims 0-15, 3.2 MB) and x_hi (dims 16-31, 3.2 MB) as SEPARATE
// arrays (separate fetch sectors!). Each block stages its 1024 edges' indices
// in LDS, then phase 0 computes partial scores vs x_lo for all its edges,
// phase 1 adds x_hi contributions. All ~3907 blocks run in ~2 co-resident
// cohorts doing identical work -> phases stay aligned chip-wide -> active
// working set ~3.2 MB -> L2 hits. Partials in LDS (same-thread write/read,
// no extra barrier). R stays fp32 from d_in (sorted edge_type -> L1-hot).
//
// Layout per phase: 8 lanes/edge, lane holds 2 dims (one f16x2 = 4 B of the
// 32 B half-row); 4-edge chunks -> 12 independent gathers in flight;
// 3x shfl_xor (1,2,4) reduces the 8-lane group.

typedef _Float16 h2 __attribute__((ext_vector_type(2)));
typedef _Float16 h4 __attribute__((ext_vector_type(4)));

#define BE 1024      // edges per block
#define NCHUNK 8     // chunks per group: 32 groups * NCHUNK * 4 = BE

__global__ __launch_bounds__(256) void convert_x(
    const float4* __restrict__ x,   // [N*8] float4 (32 floats per node)
    h4* __restrict__ xlo,           // [N*4] h4  (16 halfs per node)
    h4* __restrict__ xhi,           // [N*4] h4
    int n4)                         // N*8
{
    int i = blockIdx.x * blockDim.x + threadIdx.x;
    if (i >= n4) return;
    int node = i >> 3;
    int q    = i & 7;               // which float4 of the node's 32 floats
    float4 v = x[i];
    h4 h;
    h.x = (_Float16)v.x; h.y = (_Float16)v.y;
    h.z = (_Float16)v.z; h.w = (_Float16)v.w;
    if (q < 4) xlo[node * 4 + q]       = h;
    else       xhi[node * 4 + (q - 4)] = h;
}

__global__ __launch_bounds__(256) void distmult_kernel(
    const h2*     __restrict__ xlo,  // [N, 8] h2 units (32 B rows)
    const h2*     __restrict__ xhi,  // [N, 8] h2 units
    const float2* __restrict__ R,    // [964, 16] float2 units (128 B rows)
    const int*    __restrict__ eidx, // [2, E]
    const int*    __restrict__ etype,// [E]
    float*        __restrict__ out,  // [E]
    int E)
{
    __shared__ int   sl[BE], sr[BE], st[BE];
    __shared__ float sp[BE];

    const int base = blockIdx.x * BE;
    const int nE   = min(BE, E - base);
    const int tid  = threadIdx.x;

    // ---- stage this block's indices into LDS (coalesced int4 loads) ----
    {
        const int idx = tid * 4;                // BE/4 == 256 int4 per array
        if (idx < nE) {
            if (idx + 4 <= nE) {
                *(int4*)(sl + idx) = *(const int4*)(eidx + base + idx);
                *(int4*)(sr + idx) = *(const int4*)(eidx + E + base + idx);
                *(int4*)(st + idx) = *(const int4*)(etype + base + idx);
            } else {
                for (int j = 0; j < 4 && idx + j < nE; ++j) {
                    sl[idx + j] = eidx[base + idx + j];
                    sr[idx + j] = eidx[E + base + idx + j];
                    st[idx + j] = etype[base + idx + j];
                }
            }
        }
    }
    __syncthreads();

    const int g  = tid >> 3;    // group 0..31
    const int d4 = tid & 7;     // lane's 2-dim slot within the 16-dim half

    // ---- phase 0: x_lo (dims 0..15) -> partial scores in LDS ----
    for (int c = 0; c < NCHUNK; ++c) {
        const int el = (c * 32 + g) * 4;        // local edge base
        if (el >= nE) break;
        const int4 l4 = *(const int4*)(sl + el);
        const int4 r4 = *(const int4*)(sr + el);
        const int4 t4 = *(const int4*)(st + el);

        const h2 a0 = xlo[l4.x * 8 + d4];
        const h2 a1 = xlo[l4.y * 8 + d4];
        const h2 a2 = xlo[l4.z * 8 + d4];
        const h2 a3 = xlo[l4.w * 8 + d4];
        const h2 b0 = xlo[r4.x * 8 + d4];
        const h2 b1 = xlo[r4.y * 8 + d4];
        const h2 b2 = xlo[r4.z * 8 + d4];
        const h2 b3 = xlo[r4.w * 8 + d4];
        const float2 c0 = R[t4.x * 16 + d4];
        const float2 c1 = R[t4.y * 16 + d4];
        const float2 c2 = R[t4.z * 16 + d4];
        const float2 c3 = R[t4.w * 16 + d4];

        float s0 = fmaf((float)a0.y * c0.y, (float)b0.y, (float)a0.x * c0.x * (float)b0.x);
        float s1 = fmaf((float)a1.y * c1.y, (float)b1.y, (float)a1.x * c1.x * (float)b1.x);
        float s2 = fmaf((float)a2.y * c2.y, (float)b2.y, (float)a2.x * c2.x * (float)b2.x);
        float s3 = fmaf((float)a3.y * c3.y, (float)b3.y, (float)a3.x * c3.x * (float)b3.x);

        s0 += __shfl_xor(s0, 1); s0 += __shfl_xor(s0, 2); s0 += __shfl_xor(s0, 4);
        s1 += __shfl_xor(s1, 1); s1 += __shfl_xor(s1, 2); s1 += __shfl_xor(s1, 4);
        s2 += __shfl_xor(s2, 1); s2 += __shfl_xor(s2, 2); s2 += __shfl_xor(s2, 4);
        s3 += __shfl_xor(s3, 1); s3 += __shfl_xor(s3, 2); s3 += __shfl_xor(s3, 4);

        if (d4 == 0) {
            float4 p; p.x = s0; p.y = s1; p.z = s2; p.w = s3;
            *(float4*)(sp + el) = p;   // stride 16 B across groups: conflict-free
        }
    }
    // no __syncthreads needed: sp[el] is written and read by the same thread

    // ---- phase 1: x_hi (dims 16..31), add partial, sigmoid, store ----
    for (int c = 0; c < NCHUNK; ++c) {
        const int el = (c * 32 + g) * 4;
        if (el >= nE) break;
        const int4 l4 = *(const int4*)(sl + el);
        const int4 r4 = *(const int4*)(sr + el);
        const int4 t4 = *(const int4*)(st + el);

        const h2 a0 = xhi[l4.x * 8 + d4];
        const h2 a1 = xhi[l4.y * 8 + d4];
        const h2 a2 = xhi[l4.z * 8 + d4];
        const h2 a3 = xhi[l4.w * 8 + d4];
        const h2 b0 = xhi[r4.x * 8 + d4];
        const h2 b1 = xhi[r4.y * 8 + d4];
        const h2 b2 = xhi[r4.z * 8 + d4];
        const h2 b3 = xhi[r4.w * 8 + d4];
        const float2 c0 = R[t4.x * 16 + 8 + d4];
        const float2 c1 = R[t4.y * 16 + 8 + d4];
        const float2 c2 = R[t4.z * 16 + 8 + d4];
        const float2 c3 = R[t4.w * 16 + 8 + d4];

        float s0 = fmaf((float)a0.y * c0.y, (float)b0.y, (float)a0.x * c0.x * (float)b0.x);
        float s1 = fmaf((float)a1.y * c1.y, (float)b1.y, (float)a1.x * c1.x * (float)b1.x);
        float s2 = fmaf((float)a2.y * c2.y, (float)b2.y, (float)a2.x * c2.x * (float)b2.x);
        float s3 = fmaf((float)a3.y * c3.y, (float)b3.y, (float)a3.x * c3.x * (float)b3.x);

        s0 += __shfl_xor(s0, 1); s0 += __shfl_xor(s0, 2); s0 += __shfl_xor(s0, 4);
        s1 += __shfl_xor(s1, 1); s1 += __shfl_xor(s1, 2); s1 += __shfl_xor(s1, 4);
        s2 += __shfl_xor(s2, 1); s2 += __shfl_xor(s2, 2); s2 += __shfl_xor(s2, 4);
        s3 += __shfl_xor(s3, 1); s3 += __shfl_xor(s3, 2); s3 += __shfl_xor(s3, 4);

        if (d4 == 0) {
            const float4 p = *(const float4*)(sp + el);
            float4 o;
            o.x = __builtin_amdgcn_rcpf(1.0f + __expf(-(s0 + p.x)));
            o.y = __builtin_amdgcn_rcpf(1.0f + __expf(-(s1 + p.y)));
            o.z = __builtin_amdgcn_rcpf(1.0f + __expf(-(s2 + p.z)));
            o.w = __builtin_amdgcn_rcpf(1.0f + __expf(-(s3 + p.w)));
            if (el + 4 <= nE) {
                *(float4*)(out + base + el) = o;
            } else {
                float oo[4] = {o.x, o.y, o.z, o.w};
                for (int j = 0; j < 4 && el + j < nE; ++j) out[base + el + j] = oo[j];
            }
        }
    }
}

extern "C" void kernel_launch(void* const* d_in, const int* in_sizes, int n_in,
                              void* d_out, int out_size, void* d_ws, size_t ws_size,
                              hipStream_t stream) {
    const float* x     = (const float*)d_in[0];
    const float* R     = (const float*)d_in[1];
    const int*   eidx  = (const int*)d_in[2];
    const int*   etype = (const int*)d_in[3];
    float*       out   = (float*)d_out;

    const int E      = in_sizes[3];        // 4,000,000
    const int nNodes = in_sizes[0] / 32;   // 100,000
    const int n4     = in_sizes[0] / 4;    // float4 count = N*8

    _Float16* xlo = (_Float16*)d_ws;                 // [N*16] halfs, 3.2 MB
    _Float16* xhi = (_Float16*)d_ws + (size_t)nNodes * 16;  // 3.2 MB

    convert_x<<<(n4 + 255) / 256, 256, 0, stream>>>(
        (const float4*)x, (h4*)xlo, (h4*)xhi, n4);

    const int nBlocks = (E + BE - 1) / BE;
    distmult_kernel<<<nBlocks, 256, 0, stream>>>(
        (const h2*)xlo, (const h2*)xhi, (const float2*)R, eidx, etype, out, E);
}

// Round 5
// 165.592 us; speedup vs baseline: 1.2229x; 1.2229x over previous
//
#include <hip/hip_runtime.h>

// DistMult decoder, R4 = R2 winner + non-temporal streams.
//
// Evidence base: R2 (fp16 x, 64B rows, 4-edge unroll) hit FETCH=231MB
// (48MB compulsory indices + 183MB x-misses at the statistical 64% L2 hit
// rate for 6.4MB-on-4MiB), kernel 77.5us at ~3.0 TB/s miss-path BW.
// R3 proved sub-64B gather granules and chip-wide phase alignment both
// fail. Remaining lever: index/out streams (64MB) pollute L2 capacity that
// x needs -> load indices and store out with the `nt` (no-allocate) flag,
// leaving all of L2 to the x gather working set.
//
// Layout: 8 lanes/edge, lane holds one h4 (8B) of the 64B fp16 row; 4
// consecutive edges per group -> 12 independent gathers in flight;
// 3x shfl_xor (1,2,4) reduction within the 8-lane group; lane0 writes a
// float4 of sigmoids (non-temporal).

typedef _Float16 h4  __attribute__((ext_vector_type(4)));
typedef int      iv4 __attribute__((ext_vector_type(4)));
typedef float    fv4 __attribute__((ext_vector_type(4)));

__global__ __launch_bounds__(256) void convert_x_kernel(
    const fv4* __restrict__ x, h4* __restrict__ xh, int n4)
{
    int i = blockIdx.x * blockDim.x + threadIdx.x;
    if (i >= n4) return;
    fv4 v = x[i];   // nt not used: we WANT xh hot, and x read is one-shot streaming
    h4 h;
    h.x = (_Float16)v.x; h.y = (_Float16)v.y;
    h.z = (_Float16)v.z; h.w = (_Float16)v.w;
    xh[i] = h;
}

__global__ __launch_bounds__(256) void distmult_kernel(
    const h4*  __restrict__ xh,   // [N_NODES, 8] as h4 (64 B rows)
    const fv4* __restrict__ R,    // [N_REL, 8] as fv4 (128 B rows)
    const int* __restrict__ eidx, // [2, E]
    const int* __restrict__ etype,// [E]
    float*     __restrict__ out,  // [E]
    int E)
{
    const int tid = blockIdx.x * blockDim.x + threadIdx.x;
    const int g   = tid >> 3;       // 8-lane group id
    const int d4  = tid & 7;        // which h4 of the 32-dim row
    const int e0  = g << 2;         // first of this group's 4 edges
    if (e0 >= E) return;

    if (e0 + 4 <= E) {
        // Non-temporal index loads: streaming, do not allocate in L2.
        const iv4 l4 = __builtin_nontemporal_load((const iv4*)(eidx + e0));
        const iv4 r4 = __builtin_nontemporal_load((const iv4*)(eidx + E + e0));
        const iv4 t4 = __builtin_nontemporal_load((const iv4*)(etype + e0));

        // 12 independent gathers (8x 8B h4 + 4x 16B fv4), issued before
        // any dependent math. x gathers are CACHED (L2 capacity is theirs).
        const h4 a0 = xh[l4.x * 8 + d4];
        const h4 a1 = xh[l4.y * 8 + d4];
        const h4 a2 = xh[l4.z * 8 + d4];
        const h4 a3 = xh[l4.w * 8 + d4];
        const h4 b0 = xh[r4.x * 8 + d4];
        const h4 b1 = xh[r4.y * 8 + d4];
        const h4 b2 = xh[r4.z * 8 + d4];
        const h4 b3 = xh[r4.w * 8 + d4];
        const fv4 c0 = R[t4.x * 8 + d4];
        const fv4 c1 = R[t4.y * 8 + d4];
        const fv4 c2 = R[t4.z * 8 + d4];
        const fv4 c3 = R[t4.w * 8 + d4];

        float s0 = (float)a0.x * c0.x * (float)b0.x;
        s0 = fmaf((float)a0.y * c0.y, (float)b0.y, s0);
        s0 = fmaf((float)a0.z * c0.z, (float)b0.z, s0);
        s0 = fmaf((float)a0.w * c0.w, (float)b0.w, s0);
        float s1 = (float)a1.x * c1.x * (float)b1.x;
        s1 = fmaf((float)a1.y * c1.y, (float)b1.y, s1);
        s1 = fmaf((float)a1.z * c1.z, (float)b1.z, s1);
        s1 = fmaf((float)a1.w * c1.w, (float)b1.w, s1);
        float s2 = (float)a2.x * c2.x * (float)b2.x;
        s2 = fmaf((float)a2.y * c2.y, (float)b2.y, s2);
        s2 = fmaf((float)a2.z * c2.z, (float)b2.z, s2);
        s2 = fmaf((float)a2.w * c2.w, (float)b2.w, s2);
        float s3 = (float)a3.x * c3.x * (float)b3.x;
        s3 = fmaf((float)a3.y * c3.y, (float)b3.y, s3);
        s3 = fmaf((float)a3.z * c3.z, (float)b3.z, s3);
        s3 = fmaf((float)a3.w * c3.w, (float)b3.w, s3);

        s0 += __shfl_xor(s0, 1); s0 += __shfl_xor(s0, 2); s0 += __shfl_xor(s0, 4);
        s1 += __shfl_xor(s1, 1); s1 += __shfl_xor(s1, 2); s1 += __shfl_xor(s1, 4);
        s2 += __shfl_xor(s2, 1); s2 += __shfl_xor(s2, 2); s2 += __shfl_xor(s2, 4);
        s3 += __shfl_xor(s3, 1); s3 += __shfl_xor(s3, 2); s3 += __shfl_xor(s3, 4);

        if (d4 == 0) {
            fv4 o;
            o.x = __builtin_amdgcn_rcpf(1.0f + __expf(-s0));
            o.y = __builtin_amdgcn_rcpf(1.0f + __expf(-s1));
            o.z = __builtin_amdgcn_rcpf(1.0f + __expf(-s2));
            o.w = __builtin_amdgcn_rcpf(1.0f + __expf(-s3));
            __builtin_nontemporal_store(o, (fv4*)(out + e0));
        }
    } else {
        for (int e = e0; e < E; ++e) {
            const int l = eidx[e];
            const int r = eidx[E + e];
            const int t = etype[e];
            const h4 a = xh[l * 8 + d4];
            const h4 b = xh[r * 8 + d4];
            const fv4 c = R[t * 8 + d4];
            float s = (float)a.x * c.x * (float)b.x;
            s = fmaf((float)a.y * c.y, (float)b.y, s);
            s = fmaf((float)a.z * c.z, (float)b.z, s);
            s = fmaf((float)a.w * c.w, (float)b.w, s);
            s += __shfl_xor(s, 1); s += __shfl_xor(s, 2); s += __shfl_xor(s, 4);
            if (d4 == 0) out[e] = __builtin_amdgcn_rcpf(1.0f + __expf(-s));
        }
    }
}

extern "C" void kernel_launch(void* const* d_in, const int* in_sizes, int n_in,
                              void* d_out, int out_size, void* d_ws, size_t ws_size,
                              hipStream_t stream) {
    const float* x     = (const float*)d_in[0];
    const float* R     = (const float*)d_in[1];
    const int*   eidx  = (const int*)d_in[2];
    const int*   etype = (const int*)d_in[3];
    float*       out   = (float*)d_out;

    const int E  = in_sizes[3];       // 4,000,000 edges
    const int n4 = in_sizes[0] / 4;   // x element count / 4 (fv4 units)
    h4* xh = (h4*)d_ws;               // 6.4 MB fp16 copy of x

    convert_x_kernel<<<(n4 + 255) / 256, 256, 0, stream>>>(
        (const fv4*)x, xh, n4);

    const long long groups  = ((long long)E + 3) / 4;
    const long long threads = groups * 8;
    const int block = 256;
    const int grid  = (int)((threads + block - 1) / block);

    distmult_kernel<<<grid, block, 0, stream>>>(
        xh, (const fv4*)R, eidx, etype, out, E);
}